// Round 1
// baseline (907.506 us; speedup 1.0000x reference)
//
#include <hip/hip_runtime.h>

// ---------------- problem constants ----------------
constexpr int BB = 1024;      // batch
constexpr int DD = 2048;      // feature dim
constexpr int NN = 16384;     // memory entries
constexpr float TEMP   = 0.05f;
constexpr float LAMBDA2 = 0.5f;
constexpr float MU      = 1.0f;
constexpr float EPSN    = 1e-12f;

typedef __bf16  bf16x8  __attribute__((ext_vector_type(8)));
typedef unsigned short ushort8 __attribute__((ext_vector_type(8)));
typedef float   floatx4 __attribute__((ext_vector_type(4)));

__device__ inline unsigned short f32_to_bf16(float f) {
  unsigned int u = __builtin_bit_cast(unsigned int, f);
  u += 0x7fffu + ((u >> 16) & 1u);      // round-to-nearest-even
  return (unsigned short)(u >> 16);
}

__device__ inline float block_sum256(float v, float* sbuf) {
#pragma unroll
  for (int o = 32; o > 0; o >>= 1) v += __shfl_down(v, o, 64);
  int lane = threadIdx.x & 63, w = threadIdx.x >> 6;
  __syncthreads();
  if (lane == 0) sbuf[w] = v;
  __syncthreads();
  return sbuf[0] + sbuf[1] + sbuf[2] + sbuf[3];
}

__device__ inline float block_max256(float v, float* sbuf) {
#pragma unroll
  for (int o = 32; o > 0; o >>= 1) v = fmaxf(v, __shfl_down(v, o, 64));
  int lane = threadIdx.x & 63, w = threadIdx.x >> 6;
  __syncthreads();
  if (lane == 0) sbuf[w] = v;
  __syncthreads();
  return fmaxf(fmaxf(sbuf[0], sbuf[1]), fmaxf(sbuf[2], sbuf[3]));
}

// ---------------- K1: row-l2norm of student -> bf16, MSE vs normalized teacher ----
__global__ void __launch_bounds__(256) norm_mse_kernel(
    const float* __restrict__ X, const float* __restrict__ T,
    unsigned short* __restrict__ Xb, float* __restrict__ x2out,
    float* __restrict__ loss_acc, float wmse) {
  __shared__ float sbuf[4];
  const int b = blockIdx.x;
  const float4* xr = (const float4*)(X + (size_t)b * DD);
  const float4* tr = (const float4*)(T + (size_t)b * DD);
  float4 xv[2], tv[2];
  float sx = 0.f, st = 0.f;
#pragma unroll
  for (int i = 0; i < 2; ++i) {
    int idx = i * 256 + threadIdx.x;      // DD/4 = 512
    xv[i] = xr[idx];  tv[i] = tr[idx];
    sx += xv[i].x*xv[i].x + xv[i].y*xv[i].y + xv[i].z*xv[i].z + xv[i].w*xv[i].w;
    st += tv[i].x*tv[i].x + tv[i].y*tv[i].y + tv[i].z*tv[i].z + tv[i].w*tv[i].w;
  }
  sx = block_sum256(sx, sbuf);
  st = block_sum256(st, sbuf);
  const float rx = 1.f / fmaxf(sqrtf(sx), EPSN);
  const float rt = 1.f / fmaxf(sqrtf(st), EPSN);
  float ms = 0.f;
  ushort4* xb4 = (ushort4*)(Xb + (size_t)b * DD);
#pragma unroll
  for (int i = 0; i < 2; ++i) {
    int idx = i * 256 + threadIdx.x;
    float xn, tn, d;
    ushort4 o;
    xn = xv[i].x * rx; tn = tv[i].x * rt; d = xn - tn; ms += d * d; o.x = f32_to_bf16(xn);
    xn = xv[i].y * rx; tn = tv[i].y * rt; d = xn - tn; ms += d * d; o.y = f32_to_bf16(xn);
    xn = xv[i].z * rx; tn = tv[i].z * rt; d = xn - tn; ms += d * d; o.z = f32_to_bf16(xn);
    xn = xv[i].w * rx; tn = tv[i].w * rt; d = xn - tn; ms += d * d; o.w = f32_to_bf16(xn);
    xb4[idx] = o;
  }
  ms = block_sum256(ms, sbuf);
  if (threadIdx.x == 0) {
    x2out[b] = sx * rx * rx;
    atomicAdd(loss_acc, wmse * ms);
  }
}

// ---------------- K2: features fp32 -> bf16, row sumsq f2 ----------------
__global__ void __launch_bounds__(256) feat_kernel(
    const float* __restrict__ F, unsigned short* __restrict__ Fb,
    float* __restrict__ f2) {
  __shared__ float sbuf[4];
  const int n = blockIdx.x;
  const float4* fr = (const float4*)(F + (size_t)n * DD);
  ushort4* fb = (ushort4*)(Fb + (size_t)n * DD);
  float s = 0.f;
#pragma unroll
  for (int i = 0; i < 2; ++i) {
    int idx = i * 256 + threadIdx.x;
    float4 v = fr[idx];
    s += v.x*v.x + v.y*v.y + v.z*v.z + v.w*v.w;
    ushort4 o;
    o.x = f32_to_bf16(v.x); o.y = f32_to_bf16(v.y);
    o.z = f32_to_bf16(v.z); o.w = f32_to_bf16(v.w);
    fb[idx] = o;
  }
  s = block_sum256(s, sbuf);
  if (threadIdx.x == 0) f2[n] = s;
}

// ---------------- K3: bf16 MFMA GEMM  sim[M,N] = A[M,K] * Bm[N,K]^T ---------------
// m97 structure: 128x128 tile, BK=32, 4 waves each doing 4x4 16x16x32 MFMAs,
// global_load_lds width=16 staging.
constexpr int BM = 128, BN = 128, BK = 32;

__device__ inline void async_copy16(const void* g, void* l) {
  __builtin_amdgcn_global_load_lds(
      (const __attribute__((address_space(1))) unsigned int*)g,
      (__attribute__((address_space(3))) unsigned int*)l, 16, 0, 0);
}

__global__ void __launch_bounds__(256) gemm_bt_kernel(
    const unsigned short* __restrict__ A,    // [M][K] bf16 bits (normalized x)
    const unsigned short* __restrict__ Bm,   // [N][K] bf16 bits (features)
    float* __restrict__ C) {                 // [M][N] fp32 sim
  __shared__ __align__(16) unsigned short As[BM * BK];  // 8 KB
  __shared__ __align__(16) unsigned short Bs[BN * BK];  // 8 KB

  const int tid  = threadIdx.x;
  const int lane = tid & 63;
  const int wave = tid >> 6;
  const int quad = lane >> 4;
  const int l16  = lane & 15;
  const int wm = (wave >> 1) * 64;   // wave row offset inside tile
  const int wn = (wave & 1) * 64;    // wave col offset inside tile
  const int m0 = blockIdx.y * BM;
  const int n0 = blockIdx.x * BN;

  // staging: 512 chunks of 16B per tile; thread t covers chunks {t, 256+t}
  const int e0 = tid, e1 = 256 + tid;
  const unsigned short* gA0 = A  + (size_t)(m0 + (e0 >> 2)) * DD + (e0 & 3) * 8;
  const unsigned short* gA1 = A  + (size_t)(m0 + (e1 >> 2)) * DD + (e1 & 3) * 8;
  const unsigned short* gB0 = Bm + (size_t)(n0 + (e0 >> 2)) * DD + (e0 & 3) * 8;
  const unsigned short* gB1 = Bm + (size_t)(n0 + (e1 >> 2)) * DD + (e1 & 3) * 8;
  unsigned short* lA0 = &As[e0 * 8];
  unsigned short* lA1 = &As[e1 * 8];
  unsigned short* lB0 = &Bs[e0 * 8];
  unsigned short* lB1 = &Bs[e1 * 8];

  // LDS read addresses (fixed across K iterations)
  const unsigned short* aRd[4];
  const unsigned short* bRd[4];
#pragma unroll
  for (int r = 0; r < 4; ++r) aRd[r] = &As[(wm + r * 16 + l16) * BK + quad * 8];
#pragma unroll
  for (int c = 0; c < 4; ++c) bRd[c] = &Bs[(wn + c * 16 + l16) * BK + quad * 8];

  floatx4 acc[4][4] = {};

  for (int k0 = 0; k0 < DD; k0 += BK) {
    async_copy16(gA0, lA0);
    async_copy16(gA1, lA1);
    async_copy16(gB0, lB0);
    async_copy16(gB1, lB1);
    gA0 += BK; gA1 += BK; gB0 += BK; gB1 += BK;
    __syncthreads();   // drains vmcnt -> tiles visible

    bf16x8 af[4], bf[4];
#pragma unroll
    for (int r = 0; r < 4; ++r)
      af[r] = __builtin_bit_cast(bf16x8, *(const ushort8*)aRd[r]);
#pragma unroll
    for (int c = 0; c < 4; ++c)
      bf[c] = __builtin_bit_cast(bf16x8, *(const ushort8*)bRd[c]);
#pragma unroll
    for (int r = 0; r < 4; ++r)
#pragma unroll
      for (int c = 0; c < 4; ++c)
        acc[r][c] = __builtin_amdgcn_mfma_f32_16x16x32_bf16(af[r], bf[c], acc[r][c], 0, 0, 0);
    __syncthreads();   // protect LDS before next staging
  }

  // epilogue: C/D layout col = lane&15, row = quad*4 + reg  [m89/m91-verified]
#pragma unroll
  for (int r = 0; r < 4; ++r) {
    const int grow = m0 + wm + r * 16 + quad * 4;
#pragma unroll
    for (int c = 0; c < 4; ++c) {
      const int gcol = n0 + wn + c * 16 + l16;
#pragma unroll
      for (int i = 0; i < 4; ++i)
        C[(size_t)(grow + i) * NN + gcol] = acc[r][c][i];
    }
  }
}

// ---------------- K4: per-row CE terms from sim ----------------
// CE1 on logits = sim/TEMP ; CE2 on p = softmax(dist), dist = sqrt(max(x2+f2-2*sim,0))
__global__ void __launch_bounds__(256) rowstat_kernel(
    const float* __restrict__ sim, const float* __restrict__ f2,
    const float* __restrict__ x2, const int* __restrict__ tgt,
    float* __restrict__ loss_acc, float wce) {
  __shared__ float sbuf[4];
  const int b = blockIdx.x;
  const float4* sr  = (const float4*)(sim + (size_t)b * NN);
  const float4* f24 = (const float4*)f2;
  const float xb = x2[b];
  constexpr float INV_T = 1.0f / TEMP;

  // pass 1: maxes
  float m1 = -1e30f, m2 = -1e30f;
  for (int i = threadIdx.x; i < NN / 4; i += 256) {
    float4 s = sr[i]; float4 f = f24[i];
    m1 = fmaxf(m1, fmaxf(fmaxf(s.x, s.y), fmaxf(s.z, s.w)));
    float d0 = sqrtf(fmaxf(xb + f.x - 2.f * s.x, 0.f));
    float d1 = sqrtf(fmaxf(xb + f.y - 2.f * s.y, 0.f));
    float d2 = sqrtf(fmaxf(xb + f.z - 2.f * s.z, 0.f));
    float d3 = sqrtf(fmaxf(xb + f.w - 2.f * s.w, 0.f));
    m2 = fmaxf(m2, fmaxf(fmaxf(d0, d1), fmaxf(d2, d3)));
  }
  m1 = block_max256(m1, sbuf);
  m2 = block_max256(m2, sbuf);

  // pass 2: exp-sums
  float s1 = 0.f, s2 = 0.f;
  for (int i = threadIdx.x; i < NN / 4; i += 256) {
    float4 s = sr[i]; float4 f = f24[i];
    s1 += expf((s.x - m1) * INV_T) + expf((s.y - m1) * INV_T)
        + expf((s.z - m1) * INV_T) + expf((s.w - m1) * INV_T);
    float d0 = sqrtf(fmaxf(xb + f.x - 2.f * s.x, 0.f));
    float d1 = sqrtf(fmaxf(xb + f.y - 2.f * s.y, 0.f));
    float d2 = sqrtf(fmaxf(xb + f.z - 2.f * s.z, 0.f));
    float d3 = sqrtf(fmaxf(xb + f.w - 2.f * s.w, 0.f));
    s2 += expf(d0 - m2) + expf(d1 - m2) + expf(d2 - m2) + expf(d3 - m2);
  }
  s1 = block_sum256(s1, sbuf);
  s2 = block_sum256(s2, sbuf);
  const float invs2 = 1.f / s2;

  // pass 3: sum exp(p_n)   (p in (0,1], no overflow)
  float sp = 0.f;
  for (int i = threadIdx.x; i < NN / 4; i += 256) {
    float4 s = sr[i]; float4 f = f24[i];
    float d0 = sqrtf(fmaxf(xb + f.x - 2.f * s.x, 0.f));
    float d1 = sqrtf(fmaxf(xb + f.y - 2.f * s.y, 0.f));
    float d2 = sqrtf(fmaxf(xb + f.z - 2.f * s.z, 0.f));
    float d3 = sqrtf(fmaxf(xb + f.w - 2.f * s.w, 0.f));
    sp += expf(expf(d0 - m2) * invs2) + expf(expf(d1 - m2) * invs2)
        + expf(expf(d2 - m2) * invs2) + expf(expf(d3 - m2) * invs2);
  }
  sp = block_sum256(sp, sbuf);

  if (threadIdx.x == 0) {
    const int t = tgt[b];
    const float st = sim[(size_t)b * NN + t];
    const float dt = sqrtf(fmaxf(xb + f2[t] - 2.f * st, 0.f));
    const float pt = expf(dt - m2) * invs2;
    const float ce1 = m1 * INV_T + logf(s1) - st * INV_T;   // lse(sim/T) - sim_t/T
    const float ce2 = logf(sp) - pt;                        // lse(p) - p_t
    atomicAdd(loss_acc, wce * (ce1 + ce2));
  }
}

// ---------------- launch ----------------
extern "C" void kernel_launch(void* const* d_in, const int* in_sizes, int n_in,
                              void* d_out, int out_size, void* d_ws, size_t ws_size,
                              hipStream_t stream) {
  const float* xin[3] = {(const float*)d_in[0], (const float*)d_in[1], (const float*)d_in[2]};
  const float* tin[3] = {(const float*)d_in[3], (const float*)d_in[4], (const float*)d_in[5]};
  const int*   targets = (const int*)d_in[6];
  const float* fin[3] = {(const float*)d_in[8], (const float*)d_in[9], (const float*)d_in[10]};

  char* ws = (char*)d_ws;
  size_t off = 0;
  unsigned short* featb = (unsigned short*)(ws + off); off += (size_t)NN * DD * 2;  // 64 MiB
  float*          sim   = (float*)(ws + off);          off += (size_t)BB * NN * 4;  // 64 MiB
  unsigned short* xb    = (unsigned short*)(ws + off); off += (size_t)BB * DD * 2;  //  4 MiB
  float*          f2    = (float*)(ws + off);          off += (size_t)NN * 4;
  float*          x2    = (float*)(ws + off);          off += (size_t)BB * 4;

  float* loss = (float*)d_out;
  hipMemsetAsync(d_out, 0, sizeof(float), stream);

  const float wb[3] = {1.f - LAMBDA2, LAMBDA2, LAMBDA2};  // 0.5, 0.5, 0.5
  for (int i = 0; i < 3; ++i) {
    norm_mse_kernel<<<BB, 256, 0, stream>>>(xin[i], tin[i], xb, x2, loss,
                                            wb[i] * MU / (float)BB);
    feat_kernel<<<NN, 256, 0, stream>>>(fin[i], featb, f2);
    gemm_bt_kernel<<<dim3(NN / BN, BB / BM), 256, 0, stream>>>(xb, featb, sim);
    rowstat_kernel<<<BB, 256, 0, stream>>>(sim, f2, x2, targets, loss,
                                           wb[i] / (float)BB);
  }
}

// Round 2
// 776.535 us; speedup vs baseline: 1.1687x; 1.1687x over previous
//
#include <hip/hip_runtime.h>

// ---------------- problem constants ----------------
constexpr int BB = 1024;      // batch
constexpr int DD = 2048;      // feature dim
constexpr int NN = 16384;     // memory entries
constexpr float TEMP   = 0.05f;
constexpr float LAMBDA2 = 0.5f;
constexpr float MU      = 1.0f;
constexpr float EPSN    = 1e-12f;

typedef __bf16  bf16x8  __attribute__((ext_vector_type(8)));
typedef unsigned short ushort8 __attribute__((ext_vector_type(8)));
typedef float   floatx4 __attribute__((ext_vector_type(4)));

__device__ inline unsigned short f32_to_bf16(float f) {
  unsigned int u = __builtin_bit_cast(unsigned int, f);
  u += 0x7fffu + ((u >> 16) & 1u);      // round-to-nearest-even
  return (unsigned short)(u >> 16);
}

__device__ inline float block_sum256(float v, float* sbuf) {
#pragma unroll
  for (int o = 32; o > 0; o >>= 1) v += __shfl_down(v, o, 64);
  int lane = threadIdx.x & 63, w = threadIdx.x >> 6;
  __syncthreads();
  if (lane == 0) sbuf[w] = v;
  __syncthreads();
  return sbuf[0] + sbuf[1] + sbuf[2] + sbuf[3];
}

__device__ inline float block_max256(float v, float* sbuf) {
#pragma unroll
  for (int o = 32; o > 0; o >>= 1) v = fmaxf(v, __shfl_down(v, o, 64));
  int lane = threadIdx.x & 63, w = threadIdx.x >> 6;
  __syncthreads();
  if (lane == 0) sbuf[w] = v;
  __syncthreads();
  return fmaxf(fmaxf(sbuf[0], sbuf[1]), fmaxf(sbuf[2], sbuf[3]));
}

// ---------------- K1: row-l2norm of student -> bf16, MSE vs normalized teacher ----
__global__ void __launch_bounds__(256) norm_mse_kernel(
    const float* __restrict__ X, const float* __restrict__ T,
    unsigned short* __restrict__ Xb, float* __restrict__ x2out,
    float* __restrict__ loss_acc, float wmse) {
  __shared__ float sbuf[4];
  const int b = blockIdx.x;
  const float4* xr = (const float4*)(X + (size_t)b * DD);
  const float4* tr = (const float4*)(T + (size_t)b * DD);
  float4 xv[2], tv[2];
  float sx = 0.f, st = 0.f;
#pragma unroll
  for (int i = 0; i < 2; ++i) {
    int idx = i * 256 + threadIdx.x;      // DD/4 = 512
    xv[i] = xr[idx];  tv[i] = tr[idx];
    sx += xv[i].x*xv[i].x + xv[i].y*xv[i].y + xv[i].z*xv[i].z + xv[i].w*xv[i].w;
    st += tv[i].x*tv[i].x + tv[i].y*tv[i].y + tv[i].z*tv[i].z + tv[i].w*tv[i].w;
  }
  sx = block_sum256(sx, sbuf);
  st = block_sum256(st, sbuf);
  const float rx = 1.f / fmaxf(sqrtf(sx), EPSN);
  const float rt = 1.f / fmaxf(sqrtf(st), EPSN);
  float ms = 0.f;
  ushort4* xb4 = (ushort4*)(Xb + (size_t)b * DD);
#pragma unroll
  for (int i = 0; i < 2; ++i) {
    int idx = i * 256 + threadIdx.x;
    float xn, tn, d;
    ushort4 o;
    xn = xv[i].x * rx; tn = tv[i].x * rt; d = xn - tn; ms += d * d; o.x = f32_to_bf16(xn);
    xn = xv[i].y * rx; tn = tv[i].y * rt; d = xn - tn; ms += d * d; o.y = f32_to_bf16(xn);
    xn = xv[i].z * rx; tn = tv[i].z * rt; d = xn - tn; ms += d * d; o.z = f32_to_bf16(xn);
    xn = xv[i].w * rx; tn = tv[i].w * rt; d = xn - tn; ms += d * d; o.w = f32_to_bf16(xn);
    xb4[idx] = o;
  }
  ms = block_sum256(ms, sbuf);
  if (threadIdx.x == 0) {
    x2out[b] = sx * rx * rx;
    atomicAdd(loss_acc, wmse * ms);
  }
}

// ---------------- K2: features fp32 -> bf16, row sumsq f2 ----------------
__global__ void __launch_bounds__(256) feat_kernel(
    const float* __restrict__ F, unsigned short* __restrict__ Fb,
    float* __restrict__ f2) {
  __shared__ float sbuf[4];
  const int n = blockIdx.x;
  const float4* fr = (const float4*)(F + (size_t)n * DD);
  ushort4* fb = (ushort4*)(Fb + (size_t)n * DD);
  float s = 0.f;
#pragma unroll
  for (int i = 0; i < 2; ++i) {
    int idx = i * 256 + threadIdx.x;
    float4 v = fr[idx];
    s += v.x*v.x + v.y*v.y + v.z*v.z + v.w*v.w;
    ushort4 o;
    o.x = f32_to_bf16(v.x); o.y = f32_to_bf16(v.y);
    o.z = f32_to_bf16(v.z); o.w = f32_to_bf16(v.w);
    fb[idx] = o;
  }
  s = block_sum256(s, sbuf);
  if (threadIdx.x == 0) f2[n] = s;
}

// ---------------- K3: bf16 MFMA GEMM  sim[M,N] = A[M,K] * Bm[N,K]^T ---------------
// BK=64 + 3-bit XOR source-swizzle: row stride 128 B removes row from bank bits;
// chunk' = chunk ^ (row&7) spreads a wave's ds_read_b128 across all 32 banks
// (conflict-free). Swizzle applied on the GLOBAL source address because
// global_load_lds dest is wave-uniform-base + lane*16 (m104/m108 caveat).
constexpr int BM = 128, BN = 128, BK = 64;

__device__ inline void async_copy16(const void* g, void* l) {
  __builtin_amdgcn_global_load_lds(
      (const __attribute__((address_space(1))) unsigned int*)g,
      (__attribute__((address_space(3))) unsigned int*)l, 16, 0, 0);
}

__global__ void __launch_bounds__(256) gemm_bt_kernel(
    const unsigned short* __restrict__ A,    // [M][K] bf16 bits (normalized x)
    const unsigned short* __restrict__ Bm,   // [N][K] bf16 bits (features)
    float* __restrict__ C) {                 // [M][N] fp32 sim
  __shared__ __align__(16) unsigned short As[BM * BK];  // 16 KB
  __shared__ __align__(16) unsigned short Bs[BN * BK];  // 16 KB

  const int tid  = threadIdx.x;
  const int lane = tid & 63;
  const int wave = tid >> 6;
  const int quad = lane >> 4;
  const int l16  = lane & 15;
  const int wm = (wave >> 1) * 64;   // wave row offset inside tile
  const int wn = (wave & 1) * 64;    // wave col offset inside tile
  const int m0 = blockIdx.y * BM;
  const int n0 = blockIdx.x * BN;

  // staging: per tile 1024 A-chunks + 1024 B-chunks of 16 B; thread t does
  // chunks {c*256+t, c=0..7}; c<4 -> A, c>=4 -> B. LDS chunk (row,sc) holds
  // global chunk tc = sc ^ (row&7).
  const unsigned short* gsrc[8];
  unsigned short* ldst[8];
#pragma unroll
  for (int c = 0; c < 8; ++c) {
    const int e  = c * 256 + tid;            // 0..2047
    const int ei = (c < 4) ? e : e - 1024;   // 0..1023 within A or B
    const int row = ei >> 3;
    const int sc  = ei & 7;
    const int tc  = sc ^ (row & 7);
    const unsigned short* base =
        (c < 4) ? (A + (size_t)(m0 + row) * DD) : (Bm + (size_t)(n0 + row) * DD);
    gsrc[c] = base + tc * 8;
    ldst[c] = ((c < 4) ? As : Bs) + ei * 8;
  }

  // LDS read addresses: frag for (kstep s, tile16 r) wants global chunk
  // cc = s*4+quad of row -> LDS chunk sc = cc ^ (row&7); row&7 == l16&7.
  const unsigned short* aRd[2][4];
  const unsigned short* bRd[2][4];
#pragma unroll
  for (int s = 0; s < 2; ++s) {
    const int sc = (s * 4 + quad) ^ (l16 & 7);
#pragma unroll
    for (int r = 0; r < 4; ++r) {
      aRd[s][r] = &As[(wm + r * 16 + l16) * BK + sc * 8];
      bRd[s][r] = &Bs[(wn + r * 16 + l16) * BK + sc * 8];
    }
  }

  floatx4 acc[4][4] = {};

  for (int k0 = 0; k0 < DD; k0 += BK) {
#pragma unroll
    for (int c = 0; c < 8; ++c) {
      async_copy16(gsrc[c], ldst[c]);
      gsrc[c] += BK;
    }
    __syncthreads();   // drains vmcnt -> tiles visible

#pragma unroll
    for (int s = 0; s < 2; ++s) {
      bf16x8 af[4], bf[4];
#pragma unroll
      for (int r = 0; r < 4; ++r) {
        af[r] = __builtin_bit_cast(bf16x8, *(const ushort8*)aRd[s][r]);
        bf[r] = __builtin_bit_cast(bf16x8, *(const ushort8*)bRd[s][r]);
      }
#pragma unroll
      for (int r = 0; r < 4; ++r)
#pragma unroll
        for (int c = 0; c < 4; ++c)
          acc[r][c] = __builtin_amdgcn_mfma_f32_16x16x32_bf16(af[r], bf[c], acc[r][c], 0, 0, 0);
    }
    __syncthreads();   // protect LDS before next staging
  }

  // epilogue: C/D layout col = lane&15, row = quad*4 + reg  [m89/m91-verified]
#pragma unroll
  for (int r = 0; r < 4; ++r) {
    const int grow = m0 + wm + r * 16 + quad * 4;
#pragma unroll
    for (int c = 0; c < 4; ++c) {
      const int gcol = n0 + wn + c * 16 + l16;
#pragma unroll
      for (int i = 0; i < 4; ++i)
        C[(size_t)(grow + i) * NN + gcol] = acc[r][c][i];
    }
  }
}

// ---------------- K4: per-row CE terms from sim, single memory pass ----------------
// CE1 on logits = sim/TEMP (online LSE, no sim storage);
// CE2 on p = softmax(dist), dist = sqrt(max(x2+f2-2*sim,0)): dist cached in regs.
__global__ void __launch_bounds__(256) rowstat_kernel(
    const float* __restrict__ sim, const float* __restrict__ f2,
    const float* __restrict__ x2, const int* __restrict__ tgt,
    float* __restrict__ loss_acc, float wce) {
  __shared__ float sbuf[4];
  const int b = blockIdx.x;
  const float4* sr  = (const float4*)(sim + (size_t)b * NN);
  const float4* f24 = (const float4*)f2;
  const float xb = x2[b];
  constexpr float INV_T = 1.0f / TEMP;

  // single global pass: online LSE over sim/T; cache dist in registers
  float4 dv[16];                       // 64 VGPRs of distances
  float m1 = -1e30f, s1 = 0.f;         // running LSE state for sim*INV_T
  float m2 = -1e30f;
#pragma unroll
  for (int i = 0; i < 16; ++i) {
    const int idx = i * 256 + threadIdx.x;   // NN/4 = 4096 float4s
    float4 s = sr[idx];
    float4 f = f24[idx];
    // online LSE over logits s*INV_T
    float lm = fmaxf(fmaxf(s.x, s.y), fmaxf(s.z, s.w)) * INV_T;
    if (lm > m1) { s1 *= expf(m1 - lm); m1 = lm; }
    s1 += expf(s.x * INV_T - m1) + expf(s.y * INV_T - m1)
        + expf(s.z * INV_T - m1) + expf(s.w * INV_T - m1);
    // distances
    float4 d;
    d.x = sqrtf(fmaxf(xb + f.x - 2.f * s.x, 0.f));
    d.y = sqrtf(fmaxf(xb + f.y - 2.f * s.y, 0.f));
    d.z = sqrtf(fmaxf(xb + f.z - 2.f * s.z, 0.f));
    d.w = sqrtf(fmaxf(xb + f.w - 2.f * s.w, 0.f));
    dv[i] = d;
    m2 = fmaxf(m2, fmaxf(fmaxf(d.x, d.y), fmaxf(d.z, d.w)));
  }
  // merge LSE across block: M = max m1; s1_tot = sum s1_i * exp(m1_i - M)
  const float M1 = block_max256(m1, sbuf);
  const float s1t = block_sum256(s1 * expf(m1 - M1), sbuf);
  const float M2 = block_max256(m2, sbuf);

  float s2 = 0.f;
#pragma unroll
  for (int i = 0; i < 16; ++i) {
    float4 d = dv[i];
    s2 += expf(d.x - M2) + expf(d.y - M2) + expf(d.z - M2) + expf(d.w - M2);
  }
  const float s2t = block_sum256(s2, sbuf);
  const float invs2 = 1.f / s2t;

  float sp = 0.f;
#pragma unroll
  for (int i = 0; i < 16; ++i) {
    float4 d = dv[i];
    sp += expf(expf(d.x - M2) * invs2) + expf(expf(d.y - M2) * invs2)
        + expf(expf(d.z - M2) * invs2) + expf(expf(d.w - M2) * invs2);
  }
  const float spt = block_sum256(sp, sbuf);

  if (threadIdx.x == 0) {
    const int t = tgt[b];
    const float st = sim[(size_t)b * NN + t];
    const float dt = sqrtf(fmaxf(xb + f2[t] - 2.f * st, 0.f));
    const float pt = expf(dt - M2) * invs2;
    const float ce1 = M1 + logf(s1t) - st * INV_T;   // lse(sim/T) - sim_t/T
    const float ce2 = logf(spt) - pt;                // lse(p) - p_t
    atomicAdd(loss_acc, wce * (ce1 + ce2));
  }
}

// ---------------- launch ----------------
extern "C" void kernel_launch(void* const* d_in, const int* in_sizes, int n_in,
                              void* d_out, int out_size, void* d_ws, size_t ws_size,
                              hipStream_t stream) {
  const float* xin[3] = {(const float*)d_in[0], (const float*)d_in[1], (const float*)d_in[2]};
  const float* tin[3] = {(const float*)d_in[3], (const float*)d_in[4], (const float*)d_in[5]};
  const int*   targets = (const int*)d_in[6];
  const float* fin[3] = {(const float*)d_in[8], (const float*)d_in[9], (const float*)d_in[10]};

  char* ws = (char*)d_ws;
  size_t off = 0;
  unsigned short* featb = (unsigned short*)(ws + off); off += (size_t)NN * DD * 2;  // 64 MiB
  float*          sim   = (float*)(ws + off);          off += (size_t)BB * NN * 4;  // 64 MiB
  unsigned short* xb    = (unsigned short*)(ws + off); off += (size_t)BB * DD * 2;  //  4 MiB
  float*          f2    = (float*)(ws + off);          off += (size_t)NN * 4;
  float*          x2    = (float*)(ws + off);          off += (size_t)BB * 4;

  float* loss = (float*)d_out;
  hipMemsetAsync(d_out, 0, sizeof(float), stream);

  const float wb[3] = {1.f - LAMBDA2, LAMBDA2, LAMBDA2};  // 0.5, 0.5, 0.5
  for (int i = 0; i < 3; ++i) {
    norm_mse_kernel<<<BB, 256, 0, stream>>>(xin[i], tin[i], xb, x2, loss,
                                            wb[i] * MU / (float)BB);
    feat_kernel<<<NN, 256, 0, stream>>>(fin[i], featb, f2);
    gemm_bt_kernel<<<dim3(NN / BN, BB / BM), 256, 0, stream>>>(xb, featb, sim);
    rowstat_kernel<<<BB, 256, 0, stream>>>(sim, f2, x2, targets, loss,
                                           wb[i] / (float)BB);
  }
}

// Round 3
// 728.103 us; speedup vs baseline: 1.2464x; 1.0665x over previous
//
#include <hip/hip_runtime.h>

// ---------------- problem constants ----------------
constexpr int BB = 1024;      // batch
constexpr int DD = 2048;      // feature dim
constexpr int NN = 16384;     // memory entries
constexpr float TEMP   = 0.05f;
constexpr float LAMBDA2 = 0.5f;
constexpr float MU      = 1.0f;
constexpr float EPSN    = 1e-12f;

typedef __bf16  bf16x8  __attribute__((ext_vector_type(8)));
typedef unsigned short ushort8 __attribute__((ext_vector_type(8)));
typedef float   floatx4 __attribute__((ext_vector_type(4)));

__device__ inline unsigned short f32_to_bf16(float f) {
  unsigned int u = __builtin_bit_cast(unsigned int, f);
  u += 0x7fffu + ((u >> 16) & 1u);      // round-to-nearest-even
  return (unsigned short)(u >> 16);
}

__device__ inline float block_sum256(float v, float* sbuf) {
#pragma unroll
  for (int o = 32; o > 0; o >>= 1) v += __shfl_down(v, o, 64);
  int lane = threadIdx.x & 63, w = threadIdx.x >> 6;
  __syncthreads();
  if (lane == 0) sbuf[w] = v;
  __syncthreads();
  return sbuf[0] + sbuf[1] + sbuf[2] + sbuf[3];
}

__device__ inline float block_max256(float v, float* sbuf) {
#pragma unroll
  for (int o = 32; o > 0; o >>= 1) v = fmaxf(v, __shfl_down(v, o, 64));
  int lane = threadIdx.x & 63, w = threadIdx.x >> 6;
  __syncthreads();
  if (lane == 0) sbuf[w] = v;
  __syncthreads();
  return fmaxf(fmaxf(sbuf[0], sbuf[1]), fmaxf(sbuf[2], sbuf[3]));
}

// ---------------- K1: row-l2norm of student -> bf16, MSE vs normalized teacher ----
// Partial MSE per row -> mse_part[b] (no same-address atomics).
__global__ void __launch_bounds__(256) norm_mse_kernel(
    const float* __restrict__ X, const float* __restrict__ T,
    unsigned short* __restrict__ Xb, float* __restrict__ mse_part) {
  __shared__ float sbuf[4];
  const int b = blockIdx.x;
  const float4* xr = (const float4*)(X + (size_t)b * DD);
  const float4* tr = (const float4*)(T + (size_t)b * DD);
  float4 xv[2], tv[2];
  float sx = 0.f, st = 0.f;
#pragma unroll
  for (int i = 0; i < 2; ++i) {
    int idx = i * 256 + threadIdx.x;      // DD/4 = 512
    xv[i] = xr[idx];  tv[i] = tr[idx];
    sx += xv[i].x*xv[i].x + xv[i].y*xv[i].y + xv[i].z*xv[i].z + xv[i].w*xv[i].w;
    st += tv[i].x*tv[i].x + tv[i].y*tv[i].y + tv[i].z*tv[i].z + tv[i].w*tv[i].w;
  }
  sx = block_sum256(sx, sbuf);
  st = block_sum256(st, sbuf);
  const float rx = 1.f / fmaxf(sqrtf(sx), EPSN);
  const float rt = 1.f / fmaxf(sqrtf(st), EPSN);
  float ms = 0.f;
  ushort4* xb4 = (ushort4*)(Xb + (size_t)b * DD);
#pragma unroll
  for (int i = 0; i < 2; ++i) {
    int idx = i * 256 + threadIdx.x;
    float xn, tn, d;
    ushort4 o;
    xn = xv[i].x * rx; tn = tv[i].x * rt; d = xn - tn; ms += d * d; o.x = f32_to_bf16(xn);
    xn = xv[i].y * rx; tn = tv[i].y * rt; d = xn - tn; ms += d * d; o.y = f32_to_bf16(xn);
    xn = xv[i].z * rx; tn = tv[i].z * rt; d = xn - tn; ms += d * d; o.z = f32_to_bf16(xn);
    xn = xv[i].w * rx; tn = tv[i].w * rt; d = xn - tn; ms += d * d; o.w = f32_to_bf16(xn);
    xb4[idx] = o;
  }
  ms = block_sum256(ms, sbuf);
  if (threadIdx.x == 0) mse_part[b] = ms;
}

// ---------------- K2: features fp32 -> bf16, pure streaming convert ----------------
// f2 == 1 exactly (memory rows are unit-norm by construction) -> no reduction.
__global__ void __launch_bounds__(256) feat_convert_kernel(
    const float* __restrict__ F, unsigned short* __restrict__ Fb) {
  const int stride = gridDim.x * 256;
  const float4* fr = (const float4*)F;
  constexpr int TOT = NN * DD / 8;            // ushort8 chunks
  for (int i = blockIdx.x * 256 + threadIdx.x; i < TOT; i += stride) {
    float4 a = fr[i * 2], b = fr[i * 2 + 1];
    ushort8 o;
    o[0] = f32_to_bf16(a.x); o[1] = f32_to_bf16(a.y);
    o[2] = f32_to_bf16(a.z); o[3] = f32_to_bf16(a.w);
    o[4] = f32_to_bf16(b.x); o[5] = f32_to_bf16(b.y);
    o[6] = f32_to_bf16(b.z); o[7] = f32_to_bf16(b.w);
    *(ushort8*)(Fb + (size_t)i * 8) = o;
  }
}

// ---------------- K3: bf16 MFMA GEMM  sim[M,N] = A[M,K] * Bm[N,K]^T ---------------
// BK=64 + 3-bit XOR source-swizzle (conflict-free, verified 0 SQ_LDS_BANK_CONFLICT).
constexpr int BM = 128, BN = 128, BK = 64;

__device__ inline void async_copy16(const void* g, void* l) {
  __builtin_amdgcn_global_load_lds(
      (const __attribute__((address_space(1))) unsigned int*)g,
      (__attribute__((address_space(3))) unsigned int*)l, 16, 0, 0);
}

__global__ void __launch_bounds__(256) gemm_bt_kernel(
    const unsigned short* __restrict__ A,    // [M][K] bf16 bits (normalized x)
    const unsigned short* __restrict__ Bm,   // [N][K] bf16 bits (features)
    float* __restrict__ C) {                 // [M][N] fp32 sim
  __shared__ __align__(16) unsigned short As[BM * BK];  // 16 KB
  __shared__ __align__(16) unsigned short Bs[BN * BK];  // 16 KB

  const int tid  = threadIdx.x;
  const int lane = tid & 63;
  const int wave = tid >> 6;
  const int quad = lane >> 4;
  const int l16  = lane & 15;
  const int wm = (wave >> 1) * 64;   // wave row offset inside tile
  const int wn = (wave & 1) * 64;    // wave col offset inside tile
  const int m0 = blockIdx.y * BM;
  const int n0 = blockIdx.x * BN;

  // staging: per tile 1024 A-chunks + 1024 B-chunks of 16 B; thread t does
  // chunks {c*256+t, c=0..7}; c<4 -> A, c>=4 -> B. LDS chunk (row,sc) holds
  // global chunk tc = sc ^ (row&7)  (swizzle on the global source address).
  const unsigned short* gsrc[8];
  unsigned short* ldst[8];
#pragma unroll
  for (int c = 0; c < 8; ++c) {
    const int e  = c * 256 + tid;            // 0..2047
    const int ei = (c < 4) ? e : e - 1024;   // 0..1023 within A or B
    const int row = ei >> 3;
    const int sc  = ei & 7;
    const int tc  = sc ^ (row & 7);
    const unsigned short* base =
        (c < 4) ? (A + (size_t)(m0 + row) * DD) : (Bm + (size_t)(n0 + row) * DD);
    gsrc[c] = base + tc * 8;
    ldst[c] = ((c < 4) ? As : Bs) + ei * 8;
  }

  // LDS read addresses: frag for (kstep s, tile16 r) wants global chunk
  // cc = s*4+quad of row -> LDS chunk sc = cc ^ (row&7); row&7 == l16&7.
  const unsigned short* aRd[2][4];
  const unsigned short* bRd[2][4];
#pragma unroll
  for (int s = 0; s < 2; ++s) {
    const int sc = (s * 4 + quad) ^ (l16 & 7);
#pragma unroll
    for (int r = 0; r < 4; ++r) {
      aRd[s][r] = &As[(wm + r * 16 + l16) * BK + sc * 8];
      bRd[s][r] = &Bs[(wn + r * 16 + l16) * BK + sc * 8];
    }
  }

  floatx4 acc[4][4] = {};

  for (int k0 = 0; k0 < DD; k0 += BK) {
#pragma unroll
    for (int c = 0; c < 8; ++c) {
      async_copy16(gsrc[c], ldst[c]);
      gsrc[c] += BK;
    }
    __syncthreads();   // drains vmcnt -> tiles visible

#pragma unroll
    for (int s = 0; s < 2; ++s) {
      bf16x8 af[4], bf[4];
#pragma unroll
      for (int r = 0; r < 4; ++r) {
        af[r] = __builtin_bit_cast(bf16x8, *(const ushort8*)aRd[s][r]);
        bf[r] = __builtin_bit_cast(bf16x8, *(const ushort8*)bRd[s][r]);
      }
#pragma unroll
      for (int r = 0; r < 4; ++r)
#pragma unroll
        for (int c = 0; c < 4; ++c)
          acc[r][c] = __builtin_amdgcn_mfma_f32_16x16x32_bf16(af[r], bf[c], acc[r][c], 0, 0, 0);
    }
    __syncthreads();   // protect LDS before next staging
  }

  // epilogue: C/D layout col = lane&15, row = quad*4 + reg  [m89/m91-verified]
#pragma unroll
  for (int r = 0; r < 4; ++r) {
    const int grow = m0 + wm + r * 16 + quad * 4;
#pragma unroll
    for (int c = 0; c < 4; ++c) {
      const int gcol = n0 + wn + c * 16 + l16;
#pragma unroll
      for (int i = 0; i < 4; ++i)
        C[(size_t)(grow + i) * NN + gcol] = acc[r][c][i];
    }
  }
}

// ---------------- K4: per-row CE terms from sim, single memory pass ----------------
// x2 == f2 == 1 exactly -> dist = sqrt(max(2 - 2*sim, 0)).
// CE1 on logits = sim/TEMP (online LSE); CE2 on p = softmax(dist); dist cached in regs.
__global__ void __launch_bounds__(256) rowstat_kernel(
    const float* __restrict__ sim, const int* __restrict__ tgt,
    float* __restrict__ ce_part) {
  __shared__ float sbuf[4];
  const int b = blockIdx.x;
  const float4* sr = (const float4*)(sim + (size_t)b * NN);
  constexpr float INV_T = 1.0f / TEMP;

  float4 dv[16];                       // 64 VGPRs of distances
  float m1 = -1e30f, s1 = 0.f;         // running LSE state for sim*INV_T
  float m2 = -1e30f;
#pragma unroll
  for (int i = 0; i < 16; ++i) {
    const int idx = i * 256 + threadIdx.x;   // NN/4 = 4096 float4s
    float4 s = sr[idx];
    float lm = fmaxf(fmaxf(s.x, s.y), fmaxf(s.z, s.w)) * INV_T;
    if (lm > m1) { s1 *= expf(m1 - lm); m1 = lm; }
    s1 += expf(s.x * INV_T - m1) + expf(s.y * INV_T - m1)
        + expf(s.z * INV_T - m1) + expf(s.w * INV_T - m1);
    float4 d;
    d.x = sqrtf(fmaxf(2.f - 2.f * s.x, 0.f));
    d.y = sqrtf(fmaxf(2.f - 2.f * s.y, 0.f));
    d.z = sqrtf(fmaxf(2.f - 2.f * s.z, 0.f));
    d.w = sqrtf(fmaxf(2.f - 2.f * s.w, 0.f));
    dv[i] = d;
    m2 = fmaxf(m2, fmaxf(fmaxf(d.x, d.y), fmaxf(d.z, d.w)));
  }
  const float M1 = block_max256(m1, sbuf);
  const float s1t = block_sum256(s1 * expf(m1 - M1), sbuf);
  const float M2 = block_max256(m2, sbuf);

  float s2 = 0.f;
#pragma unroll
  for (int i = 0; i < 16; ++i) {
    float4 d = dv[i];
    s2 += expf(d.x - M2) + expf(d.y - M2) + expf(d.z - M2) + expf(d.w - M2);
  }
  const float s2t = block_sum256(s2, sbuf);
  const float invs2 = 1.f / s2t;

  float sp = 0.f;
#pragma unroll
  for (int i = 0; i < 16; ++i) {
    float4 d = dv[i];
    sp += expf(expf(d.x - M2) * invs2) + expf(expf(d.y - M2) * invs2)
        + expf(expf(d.z - M2) * invs2) + expf(expf(d.w - M2) * invs2);
  }
  const float spt = block_sum256(sp, sbuf);

  if (threadIdx.x == 0) {
    const int t = tgt[b];
    const float st = sim[(size_t)b * NN + t];
    const float dt = sqrtf(fmaxf(2.f - 2.f * st, 0.f));
    const float pt = expf(dt - M2) * invs2;
    const float ce1 = M1 + logf(s1t) - st * INV_T;   // lse(sim/T) - sim_t/T
    const float ce2 = logf(spt) - pt;                // lse(p) - p_t
    ce_part[b] = ce1 + ce2;
  }
}

// ---------------- K5: final weighted reduce of all partials -> d_out ----------------
__global__ void __launch_bounds__(256) final_reduce_kernel(
    const float* __restrict__ mse_part,   // [3*BB]
    const float* __restrict__ ce_part,    // [3*BB]
    float* __restrict__ loss) {
  __shared__ float sbuf[4];
  float s = 0.f;
  for (int i = threadIdx.x; i < 3 * BB; i += 256) {
    const float w = (i < BB) ? (1.0f - LAMBDA2) : LAMBDA2;
    s += w * (MU * mse_part[i] + ce_part[i]);
  }
  s = block_sum256(s, sbuf);
  if (threadIdx.x == 0) loss[0] = s * (1.0f / (float)BB);
}

// ---------------- launch ----------------
extern "C" void kernel_launch(void* const* d_in, const int* in_sizes, int n_in,
                              void* d_out, int out_size, void* d_ws, size_t ws_size,
                              hipStream_t stream) {
  const float* xin[3] = {(const float*)d_in[0], (const float*)d_in[1], (const float*)d_in[2]};
  const float* tin[3] = {(const float*)d_in[3], (const float*)d_in[4], (const float*)d_in[5]};
  const int*   targets = (const int*)d_in[6];
  const float* fin[3] = {(const float*)d_in[8], (const float*)d_in[9], (const float*)d_in[10]};

  char* ws = (char*)d_ws;
  size_t off = 0;
  unsigned short* featb = (unsigned short*)(ws + off); off += (size_t)NN * DD * 2;  // 64 MiB
  float*          sim   = (float*)(ws + off);          off += (size_t)BB * NN * 4;  // 64 MiB
  unsigned short* xb    = (unsigned short*)(ws + off); off += (size_t)BB * DD * 2;  //  4 MiB
  float*          msep  = (float*)(ws + off);          off += (size_t)3 * BB * 4;
  float*          cep   = (float*)(ws + off);          off += (size_t)3 * BB * 4;

  for (int i = 0; i < 3; ++i) {
    norm_mse_kernel<<<BB, 256, 0, stream>>>(xin[i], tin[i], xb, msep + i * BB);
    feat_convert_kernel<<<4096, 256, 0, stream>>>(fin[i], featb);
    gemm_bt_kernel<<<dim3(NN / BN, BB / BM), 256, 0, stream>>>(xb, featb, sim);
    rowstat_kernel<<<BB, 256, 0, stream>>>(sim, targets, cep + i * BB);
  }
  final_reduce_kernel<<<1, 256, 0, stream>>>(msep, cep, (float*)d_out);
}